// Round 3
// baseline (388.864 us; speedup 1.0000x reference)
//
#include <hip/hip_runtime.h>
#include <hip/hip_bf16.h>

#define SEQ 2048
#define DH 64
#define QB 64           // q rows per block (16 per wave)
#define KB 64           // kv rows per tile
#define PAD 72          // LDS row stride in bf16 elems (64 + 8); 144B keeps 16B alignment
#define NT (SEQ / KB)

typedef __attribute__((ext_vector_type(8))) short bf16x8;
typedef __attribute__((ext_vector_type(4))) short bf16x4;
typedef __attribute__((ext_vector_type(4))) float f32x4;

__device__ __forceinline__ short f2bf(float x) {
    __hip_bfloat16 h = __float2bfloat16(x);   // RNE; compiler packs pairs (v_cvt_pk_bf16_f32)
    union { __hip_bfloat16 h; short s; } u; u.h = h;
    return u.s;
}

__global__ __launch_bounds__(256)
void attn_fwd_23562190586278(const float* __restrict__ Qp,
                             const float* __restrict__ Kp,
                             const float* __restrict__ Vp,
                             float* __restrict__ Op) {
    __shared__ __align__(16) short k_lds[KB * PAD];        // [kv][d]
    __shared__ __align__(16) short vT_lds[DH * PAD];       // [d][kv]
    __shared__ __align__(16) short p_lds[4 * 16 * PAD];    // per-wave [q(16)][kv(64)]

    const int tid  = threadIdx.x;
    const int wave = tid >> 6;
    const int lane = tid & 63;
    const int g    = lane >> 4;     // 0..3
    const int c    = lane & 15;     // 0..15

    // T1: chunked XCD swizzle (bijective: 2048 % 8 == 0). Same-head q-blocks
    // land on one XCD -> K/V re-reads hit that XCD's L2.
    const int hw_bid = blockIdx.x;
    const int chunk  = gridDim.x >> 3;                  // 2048/8 = 256
    const int L      = (hw_bid & 7) * chunk + (hw_bid >> 3);
    const int head   = L >> 5;                          // 32 q-blocks per head
    const int q0     = (L & 31) * QB + wave * 16;

    const size_t base = (size_t)head * SEQ * DH;

    // ---- hoist Q fragments (A layout: row = lane&15, k = 8*(lane>>4)+j)
    // scale folds 1/sqrt(64) AND log2(e): softmax runs in exp2 domain.
    const float qscale = 0.125f * 1.44269504088896f;
    bf16x8 qf[2];
    {
        const float* qrow = Qp + base + (size_t)(q0 + c) * DH;
        #pragma unroll
        for (int ch = 0; ch < 2; ++ch) {
            const float4 a = *(const float4*)(qrow + ch * 32 + g * 8);
            const float4 b = *(const float4*)(qrow + ch * 32 + g * 8 + 4);
            bf16x8 r;
            r[0] = f2bf(a.x * qscale); r[1] = f2bf(a.y * qscale);
            r[2] = f2bf(a.z * qscale); r[3] = f2bf(a.w * qscale);
            r[4] = f2bf(b.x * qscale); r[5] = f2bf(b.y * qscale);
            r[6] = f2bf(b.z * qscale); r[7] = f2bf(b.w * qscale);
            qf[ch] = r;
        }
    }

    f32x4 o_acc[4] = {};             // row = 4*g + reg, col = d16*16 + c
    float m_run[4], l_run[4];
    #pragma unroll
    for (int r = 0; r < 4; ++r) { m_run[r] = -1e30f; l_run[r] = 0.f; }

    // K staging map: one row, 16 contiguous cols per thread
    const int krow = tid >> 2;           // 0..63
    const int kcol = (tid & 3) << 4;     // 0,16,32,48
    // V staging map: 4 rows x 4 cols per thread (enables b64 transpose writes)
    const int vrow = (tid >> 4) << 2;    // 0,4,...,60
    const int vcol = (tid & 15) << 2;    // 0,4,...,60

    const float* kptr = Kp + base + (size_t)krow * DH + kcol;
    const float* vptr = Vp + base + (size_t)vrow * DH + vcol;

    // T14 prologue: tile 0 loads into registers
    float4 kr[4], vr[4];
    #pragma unroll
    for (int i = 0; i < 4; ++i) {
        kr[i] = ((const float4*)kptr)[i];
        vr[i] = *(const float4*)(vptr + i * DH);
    }

    for (int t = 0; t < NT; ++t) {
        // ---- convert + write current tile from registers ----
        {
            bf16x8 lo, hi;
            lo[0]=f2bf(kr[0].x); lo[1]=f2bf(kr[0].y); lo[2]=f2bf(kr[0].z); lo[3]=f2bf(kr[0].w);
            lo[4]=f2bf(kr[1].x); lo[5]=f2bf(kr[1].y); lo[6]=f2bf(kr[1].z); lo[7]=f2bf(kr[1].w);
            hi[0]=f2bf(kr[2].x); hi[1]=f2bf(kr[2].y); hi[2]=f2bf(kr[2].z); hi[3]=f2bf(kr[2].w);
            hi[4]=f2bf(kr[3].x); hi[5]=f2bf(kr[3].y); hi[6]=f2bf(kr[3].z); hi[7]=f2bf(kr[3].w);
            *(bf16x8*)&k_lds[krow * PAD + kcol]     = lo;
            *(bf16x8*)&k_lds[krow * PAD + kcol + 8] = hi;

            // V transpose: pack 4 kv values of one d-column into a b64 write
            #pragma unroll
            for (int j = 0; j < 4; ++j) {
                bf16x4 w;
                w[0] = f2bf(((const float*)&vr[0])[j]);
                w[1] = f2bf(((const float*)&vr[1])[j]);
                w[2] = f2bf(((const float*)&vr[2])[j]);
                w[3] = f2bf(((const float*)&vr[3])[j]);
                *(bf16x4*)&vT_lds[(vcol + j) * PAD + vrow] = w;
            }
        }
        __syncthreads();

        // T14: issue next tile's global loads now; consumed at next loop top,
        // latency hides under this tile's MFMA + softmax.
        if (t + 1 < NT) {
            const float* kn = kptr + (size_t)(t + 1) * KB * DH;
            const float* vn = vptr + (size_t)(t + 1) * KB * DH;
            #pragma unroll
            for (int i = 0; i < 4; ++i) {
                kr[i] = ((const float4*)kn)[i];
                vr[i] = *(const float4*)(vn + i * DH);
            }
        }

        // ---- S' = (QK^T) * scale * log2e  (4 col-frags of 16 kv) ----
        f32x4 sf[4];
        #pragma unroll
        for (int f = 0; f < 4; ++f) {
            f32x4 acc = {0.f, 0.f, 0.f, 0.f};
            #pragma unroll
            for (int ch = 0; ch < 2; ++ch) {
                bf16x8 kf = *(const bf16x8*)&k_lds[(f * 16 + c) * PAD + ch * 32 + g * 8];
                acc = __builtin_amdgcn_mfma_f32_16x16x32_bf16(qf[ch], kf, acc, 0, 0, 0);
            }
            sf[f] = acc;
        }

        // ---- online softmax in exp2 domain (row r = 4*g + reg; reduce over 16-lane col group) ----
        short* pw = &p_lds[wave * 16 * PAD];
        #pragma unroll
        for (int r = 0; r < 4; ++r) {
            float mx = fmaxf(fmaxf(sf[0][r], sf[1][r]), fmaxf(sf[2][r], sf[3][r]));
            #pragma unroll
            for (int mk = 1; mk < 16; mk <<= 1) mx = fmaxf(mx, __shfl_xor(mx, mk));
            const float mnew  = fmaxf(m_run[r], mx);
            const float alpha = exp2f(m_run[r] - mnew);
            m_run[r] = mnew;
            float rsum = 0.f;
            #pragma unroll
            for (int f = 0; f < 4; ++f) {
                float p = exp2f(sf[f][r] - mnew);
                sf[f][r] = p;
                rsum += p;
            }
            #pragma unroll
            for (int mk = 1; mk < 16; mk <<= 1) rsum += __shfl_xor(rsum, mk);
            l_run[r] = l_run[r] * alpha + rsum;
            #pragma unroll
            for (int d16 = 0; d16 < 4; ++d16) o_acc[d16][r] *= alpha;
            #pragma unroll
            for (int f = 0; f < 4; ++f)
                pw[(4 * g + r) * PAD + f * 16 + c] = f2bf(sf[f][r]);
        }

        asm volatile("" ::: "memory");  // order P writes before P reads (same wave: LDS is in-order)

        // ---- O += P V  (A = P, B = V^T rows) ----
        #pragma unroll
        for (int ch = 0; ch < 2; ++ch) {
            bf16x8 pf = *(const bf16x8*)&pw[c * PAD + ch * 32 + g * 8];
            #pragma unroll
            for (int d16 = 0; d16 < 4; ++d16) {
                bf16x8 vf = *(const bf16x8*)&vT_lds[(d16 * 16 + c) * PAD + ch * 32 + g * 8];
                o_acc[d16] = __builtin_amdgcn_mfma_f32_16x16x32_bf16(pf, vf, o_acc[d16], 0, 0, 0);
            }
        }
        __syncthreads();   // all reads of this tile done before next tile's writes
    }

    // ---- epilogue: divide by l, store fp32 ----
    #pragma unroll
    for (int r = 0; r < 4; ++r) {
        const float inv = 1.0f / l_run[r];
        float* orow = Op + base + (size_t)(q0 + 4 * g + r) * DH;
        #pragma unroll
        for (int d16 = 0; d16 < 4; ++d16)
            orow[d16 * 16 + c] = o_acc[d16][r] * inv;
    }
}

extern "C" void kernel_launch(void* const* d_in, const int* in_sizes, int n_in,
                              void* d_out, int out_size, void* d_ws, size_t ws_size,
                              hipStream_t stream) {
    const float* q = (const float*)d_in[0];
    const float* k = (const float*)d_in[1];
    const float* v = (const float*)d_in[2];
    float* out = (float*)d_out;
    const int bh = in_sizes[0] / (SEQ * DH);   // B*H = 64
    dim3 grid((SEQ / QB) * bh);                // 2048 blocks, flattened for XCD swizzle
    attn_fwd_23562190586278<<<grid, 256, 0, stream>>>(q, k, v, out);
}

// Round 4
// 296.150 us; speedup vs baseline: 1.3131x; 1.3131x over previous
//
#include <hip/hip_runtime.h>
#include <hip/hip_bf16.h>
#include <stdint.h>

#define SEQ 2048
#define DH 64
#define QB 64           // q rows per block (16 per wave)
#define KB 64           // kv rows per tile
#define NT (SEQ / KB)
#define PAD 72          // (fallback kernel only)

typedef __attribute__((ext_vector_type(8))) short bf16x8;
typedef __attribute__((ext_vector_type(4))) short bf16x4;
typedef __attribute__((ext_vector_type(4))) float f32x4;

__device__ __forceinline__ short f2bf(float x) {
    union { __hip_bfloat16 h; short s; } u; u.h = __float2bfloat16(x); return u.s;
}
__device__ __forceinline__ int packbf(float lo, float hi) {
    return (int)((unsigned)(unsigned short)f2bf(lo) | ((unsigned)(unsigned short)f2bf(hi) << 16));
}

// ---- global_load_lds: 16B/lane, dest = wave-uniform LDS base + lane*16 ----
typedef __attribute__((address_space(3))) unsigned int       lds_u32;
typedef const __attribute__((address_space(1))) unsigned int g_u32;
__device__ __forceinline__ void gload16(const void* g, const void* lds_base) {
    // int-detour casts == what LLVM's addrspacecast does (generic LDS va low32 = offset)
    __builtin_amdgcn_global_load_lds((g_u32*)(unsigned long long)g,
                                     (lds_u32*)(unsigned int)(unsigned long long)lds_base,
                                     16, 0, 0);
}

// ================= prep kernels =================
__global__ __launch_bounds__(256)
void prep_k_bf16(const float* __restrict__ K, short* __restrict__ Kb, int n8) {
    int i = blockIdx.x * 256 + threadIdx.x;
    if (i >= n8) return;
    float4 a = ((const float4*)K)[i * 2], b = ((const float4*)K)[i * 2 + 1];
    bf16x8 r;
    r[0]=f2bf(a.x); r[1]=f2bf(a.y); r[2]=f2bf(a.z); r[3]=f2bf(a.w);
    r[4]=f2bf(b.x); r[5]=f2bf(b.y); r[6]=f2bf(b.z); r[7]=f2bf(b.w);
    ((bf16x8*)Kb)[i] = r;
}

__global__ __launch_bounds__(256)
void prep_v_transpose(const float* __restrict__ V, short* __restrict__ VT) {
    __shared__ short tile[64][72];                 // [s_local][d], pad 72
    const int head = blockIdx.x >> 5;              // 32 s-tiles per head
    const int s0   = (blockIdx.x & 31) * 64;
    const int tid  = threadIdx.x;
    {   // load 64x64 fp32 coalesced -> bf16 tile
        const int r = tid >> 2, cb = (tid & 3) * 16;
        const float* src = V + ((size_t)head * SEQ + s0 + r) * DH + cb;
        float4 f0 = ((const float4*)src)[0], f1 = ((const float4*)src)[1];
        float4 f2 = ((const float4*)src)[2], f3 = ((const float4*)src)[3];
        bf16x8 lo, hi;
        lo[0]=f2bf(f0.x); lo[1]=f2bf(f0.y); lo[2]=f2bf(f0.z); lo[3]=f2bf(f0.w);
        lo[4]=f2bf(f1.x); lo[5]=f2bf(f1.y); lo[6]=f2bf(f1.z); lo[7]=f2bf(f1.w);
        hi[0]=f2bf(f2.x); hi[1]=f2bf(f2.y); hi[2]=f2bf(f2.z); hi[3]=f2bf(f2.w);
        hi[4]=f2bf(f3.x); hi[5]=f2bf(f3.y); hi[6]=f2bf(f3.z); hi[7]=f2bf(f3.w);
        *(bf16x8*)&tile[r][cb]     = lo;
        *(bf16x8*)&tile[r][cb + 8] = hi;
    }
    __syncthreads();
    {   // store transposed [d][s] coalesced
        const int d = tid >> 2, sb = (tid & 3) * 16;
        bf16x8 lo, hi;
        #pragma unroll
        for (int j = 0; j < 8; ++j) lo[j] = tile[sb + j][d];
        #pragma unroll
        for (int j = 0; j < 8; ++j) hi[j] = tile[sb + 8 + j][d];
        short* dst = VT + ((size_t)head * DH + d) * SEQ + s0 + sb;
        *(bf16x8*)dst       = lo;
        *(bf16x8*)(dst + 8) = hi;
    }
}

// ================= main attention (v4) =================
__global__ __launch_bounds__(256)
void attn_fwd_v4(const float* __restrict__ Qp,
                 const short* __restrict__ Kb,
                 const short* __restrict__ VTb,
                 float* __restrict__ Op) {
    __shared__ __align__(16) short k_lds [2][KB * DH];   // [kv][d], swizzled content
    __shared__ __align__(16) short vt_lds[2][DH * KB];   // [d][kv], swizzled content

    const int tid  = threadIdx.x;
    const int wave = tid >> 6;
    const int lane = tid & 63;
    const int g    = lane >> 4;       // 0..3
    const int c    = lane & 15;       // 0..15

    // T1 chunked XCD swizzle (bijective: grid%8==0)
    const int chunk = gridDim.x >> 3;
    const int L     = (blockIdx.x & 7) * chunk + (blockIdx.x >> 3);
    const int head  = L >> 5;
    const int q0    = (L & 31) * QB + wave * 16;

    const size_t baseF  = (size_t)head * SEQ * DH;   // fp32 Q/O
    const short* Kh  = Kb  + baseF;                  // [s][d] bf16
    const short* VTh = VTb + (size_t)head * DH * SEQ; // [d][s] bf16

    // Q fragments (B-operand: col=lane&15=q, k=8g+j), scale = 1/8 * log2(e)
    const float qscale = 0.125f * 1.44269504088896f;
    bf16x8 qf[2];
    {
        const float* qrow = Qp + baseF + (size_t)(q0 + c) * DH;
        #pragma unroll
        for (int ch = 0; ch < 2; ++ch) {
            float4 a = *(const float4*)(qrow + ch * 32 + g * 8);
            float4 b = *(const float4*)(qrow + ch * 32 + g * 8 + 4);
            bf16x8 r;
            r[0]=f2bf(a.x*qscale); r[1]=f2bf(a.y*qscale); r[2]=f2bf(a.z*qscale); r[3]=f2bf(a.w*qscale);
            r[4]=f2bf(b.x*qscale); r[5]=f2bf(b.y*qscale); r[6]=f2bf(b.z*qscale); r[7]=f2bf(b.w*qscale);
            qf[ch] = r;
        }
    }

    f32x4 o_acc[4] = {};          // C: col=c=d-col, row=4g+reg=q-row
    float m_run = -1e30f, l_run = 0.f;   // lane's softmax row = q0 + c

    // staging geometry: per instr, 8 rows x 8 chunks(16B); src chunk pre-swizzled
    const int r8   = lane >> 3, c8 = lane & 7;
    const int csw8 = ((c8 ^ r8) << 3);               // swizzled chunk, in elems
    const int rowb = 16 * wave;

    #define STAGE(T, BUF) do {                                                        \
        _Pragma("unroll")                                                             \
        for (int i = 0; i < 2; ++i) {                                                 \
            gload16(Kh  + ((size_t)((T) * KB + rowb + 8 * i + r8) * DH + csw8),       \
                    &k_lds[BUF][(rowb + 8 * i) * DH]);                                \
            gload16(VTh + ((size_t)(rowb + 8 * i + r8) * SEQ + (T) * KB + csw8),      \
                    &vt_lds[BUF][(rowb + 8 * i) * DH]);                               \
        } } while (0)

    STAGE(0, 0);
    __syncthreads();                 // compiler drains vmcnt(0) before barrier
    int cur = 0;

    for (int t = 0; t < NT; ++t) {
        if (t + 1 < NT) STAGE(t + 1, cur ^ 1);   // issue next tile first (T3)

        // ---- S^T = K Q^T (swapped): A=K rows=kv, B=Q cols=q ----
        // result: col=c=q, row=4g+r=kv(within 16-frag), frag f -> kv=16f+4g+r
        f32x4 sf[4];
        #pragma unroll
        for (int f = 0; f < 4; ++f) {
            f32x4 acc = {0.f, 0.f, 0.f, 0.f};
            #pragma unroll
            for (int ch = 0; ch < 2; ++ch) {
                bf16x8 kf = *(const bf16x8*)
                    &k_lds[cur][(16 * f + c) * DH + (((4 * ch + g) ^ (c & 7)) << 3)];
                acc = __builtin_amdgcn_mfma_f32_16x16x32_bf16(kf, qf[ch], acc, 0, 0, 0);
            }
            sf[f] = acc;
        }

        // ---- online softmax, in-register (row q=c; partners = lanes c+16k) ----
        float mx = sf[0][0];
        #pragma unroll
        for (int f = 0; f < 4; ++f)
            #pragma unroll
            for (int r = 0; r < 4; ++r) mx = fmaxf(mx, sf[f][r]);
        mx = fmaxf(mx, __shfl_xor(mx, 16));
        mx = fmaxf(mx, __shfl_xor(mx, 32));
        const float mnew  = fmaxf(m_run, mx);
        const float alpha = exp2f(m_run - mnew);
        m_run = mnew;
        float rsum = 0.f;
        #pragma unroll
        for (int f = 0; f < 4; ++f)
            #pragma unroll
            for (int r = 0; r < 4; ++r) {
                float p = exp2f(sf[f][r] - mnew);
                sf[f][r] = p; rsum += p;
            }
        rsum += __shfl_xor(rsum, 16);
        rsum += __shfl_xor(rsum, 32);
        l_run = l_run * alpha + rsum;

        // ---- P -> PV A-fragments via bpermute (no LDS) ----
        // pd[f][rt] = bf16 pair at kv = 16f+4g+2rt(,+1), q=c
        int pd[4][2];
        #pragma unroll
        for (int f = 0; f < 4; ++f) {
            pd[f][0] = packbf(sf[f][0], sf[f][1]);
            pd[f][1] = packbf(sf[f][2], sf[f][3]);
        }
        // a[ch][jt] <- lane c+16*(2(g&1)+(jt>>1)), reg pd[2ch+(g>>1)][jt&1]
        const int srcb = c + ((g & 1) << 5);
        const bool hi2 = (g >> 1) != 0;
        int a_dw[2][4];
        #pragma unroll
        for (int ch = 0; ch < 2; ++ch)
            #pragma unroll
            for (int jt = 0; jt < 4; ++jt) {
                int src = srcb + ((jt >> 1) << 4);
                int tA = __shfl(pd[2 * ch][jt & 1], src);
                int tB = __shfl(pd[2 * ch + 1][jt & 1], src);
                a_dw[ch][jt] = hi2 ? tB : tA;
            }

        // ---- rescale O by alpha of rows 4g+r ----
        float al[4];
        #pragma unroll
        for (int r = 0; r < 4; ++r) al[r] = __shfl(alpha, 4 * g + r);
        #pragma unroll
        for (int d16 = 0; d16 < 4; ++d16)
            #pragma unroll
            for (int r = 0; r < 4; ++r) o_acc[d16][r] *= al[r];

        // ---- O += P V : A=P (row=q=c, k=kv), B=V^T (col=d=c, k=kv) ----
        #pragma unroll
        for (int ch = 0; ch < 2; ++ch) {
            union { int d[4]; bf16x8 v; } au;
            #pragma unroll
            for (int jt = 0; jt < 4; ++jt) au.d[jt] = a_dw[ch][jt];
            #pragma unroll
            for (int d16 = 0; d16 < 4; ++d16) {
                bf16x8 vf = *(const bf16x8*)
                    &vt_lds[cur][(16 * d16 + c) * DH + (((4 * ch + g) ^ (c & 7)) << 3)];
                o_acc[d16] = __builtin_amdgcn_mfma_f32_16x16x32_bf16(au.v, vf, o_acc[d16], 0, 0, 0);
            }
        }

        __syncthreads();   // drains stage vmcnt + all waves done reading buf[cur]
        cur ^= 1;
    }
    #undef STAGE

    // ---- epilogue ----
    #pragma unroll
    for (int r = 0; r < 4; ++r) {
        float li  = __shfl(l_run, 4 * g + r);
        float inv = 1.0f / li;
        float* orow = Op + baseF + (size_t)(q0 + 4 * g + r) * DH;
        #pragma unroll
        for (int d16 = 0; d16 < 4; ++d16)
            orow[d16 * 16 + c] = o_acc[d16][r] * inv;
    }
}

// ================= fallback (v3, known-pass) — used only if ws too small =================
__global__ __launch_bounds__(256)
void attn_fwd_v3(const float* __restrict__ Qp, const float* __restrict__ Kp,
                 const float* __restrict__ Vp, float* __restrict__ Op) {
    __shared__ __align__(16) short k_lds[KB * PAD];
    __shared__ __align__(16) short vT_lds[DH * PAD];
    __shared__ __align__(16) short p_lds[4 * 16 * PAD];
    const int tid = threadIdx.x, wave = tid >> 6, lane = tid & 63;
    const int g = lane >> 4, c = lane & 15;
    const int chunk = gridDim.x >> 3;
    const int L = (blockIdx.x & 7) * chunk + (blockIdx.x >> 3);
    const int head = L >> 5;
    const int q0 = (L & 31) * QB + wave * 16;
    const size_t base = (size_t)head * SEQ * DH;
    const float qscale = 0.125f * 1.44269504088896f;
    bf16x8 qf[2];
    {
        const float* qrow = Qp + base + (size_t)(q0 + c) * DH;
        #pragma unroll
        for (int ch = 0; ch < 2; ++ch) {
            float4 a = *(const float4*)(qrow + ch * 32 + g * 8);
            float4 b = *(const float4*)(qrow + ch * 32 + g * 8 + 4);
            bf16x8 r;
            r[0]=f2bf(a.x*qscale); r[1]=f2bf(a.y*qscale); r[2]=f2bf(a.z*qscale); r[3]=f2bf(a.w*qscale);
            r[4]=f2bf(b.x*qscale); r[5]=f2bf(b.y*qscale); r[6]=f2bf(b.z*qscale); r[7]=f2bf(b.w*qscale);
            qf[ch] = r;
        }
    }
    f32x4 o_acc[4] = {};
    float m_run[4], l_run[4];
    #pragma unroll
    for (int r = 0; r < 4; ++r) { m_run[r] = -1e30f; l_run[r] = 0.f; }
    const int krow = tid >> 2, kcol = (tid & 3) << 4;
    const int vrow = (tid >> 4) << 2, vcol = (tid & 15) << 2;
    const float* kptr = Kp + base + (size_t)krow * DH + kcol;
    const float* vptr = Vp + base + (size_t)vrow * DH + vcol;
    float4 kr[4], vr[4];
    #pragma unroll
    for (int i = 0; i < 4; ++i) { kr[i] = ((const float4*)kptr)[i]; vr[i] = *(const float4*)(vptr + i * DH); }
    for (int t = 0; t < NT; ++t) {
        {
            bf16x8 lo, hi;
            lo[0]=f2bf(kr[0].x); lo[1]=f2bf(kr[0].y); lo[2]=f2bf(kr[0].z); lo[3]=f2bf(kr[0].w);
            lo[4]=f2bf(kr[1].x); lo[5]=f2bf(kr[1].y); lo[6]=f2bf(kr[1].z); lo[7]=f2bf(kr[1].w);
            hi[0]=f2bf(kr[2].x); hi[1]=f2bf(kr[2].y); hi[2]=f2bf(kr[2].z); hi[3]=f2bf(kr[2].w);
            hi[4]=f2bf(kr[3].x); hi[5]=f2bf(kr[3].y); hi[6]=f2bf(kr[3].z); hi[7]=f2bf(kr[3].w);
            *(bf16x8*)&k_lds[krow * PAD + kcol] = lo;
            *(bf16x8*)&k_lds[krow * PAD + kcol + 8] = hi;
            #pragma unroll
            for (int j = 0; j < 4; ++j) {
                bf16x4 w;
                w[0]=f2bf(((const float*)&vr[0])[j]); w[1]=f2bf(((const float*)&vr[1])[j]);
                w[2]=f2bf(((const float*)&vr[2])[j]); w[3]=f2bf(((const float*)&vr[3])[j]);
                *(bf16x4*)&vT_lds[(vcol + j) * PAD + vrow] = w;
            }
        }
        __syncthreads();
        if (t + 1 < NT) {
            const float* kn = kptr + (size_t)(t + 1) * KB * DH;
            const float* vn = vptr + (size_t)(t + 1) * KB * DH;
            #pragma unroll
            for (int i = 0; i < 4; ++i) { kr[i] = ((const float4*)kn)[i]; vr[i] = *(const float4*)(vn + i * DH); }
        }
        f32x4 sf[4];
        #pragma unroll
        for (int f = 0; f < 4; ++f) {
            f32x4 acc = {0.f, 0.f, 0.f, 0.f};
            #pragma unroll
            for (int ch = 0; ch < 2; ++ch) {
                bf16x8 kf = *(const bf16x8*)&k_lds[(f * 16 + c) * PAD + ch * 32 + g * 8];
                acc = __builtin_amdgcn_mfma_f32_16x16x32_bf16(qf[ch], kf, acc, 0, 0, 0);
            }
            sf[f] = acc;
        }
        short* pw = &p_lds[wave * 16 * PAD];
        #pragma unroll
        for (int r = 0; r < 4; ++r) {
            float mx = fmaxf(fmaxf(sf[0][r], sf[1][r]), fmaxf(sf[2][r], sf[3][r]));
            #pragma unroll
            for (int mk = 1; mk < 16; mk <<= 1) mx = fmaxf(mx, __shfl_xor(mx, mk));
            const float mnew = fmaxf(m_run[r], mx);
            const float alpha = exp2f(m_run[r] - mnew);
            m_run[r] = mnew;
            float rsum = 0.f;
            #pragma unroll
            for (int f = 0; f < 4; ++f) { float p = exp2f(sf[f][r] - mnew); sf[f][r] = p; rsum += p; }
            #pragma unroll
            for (int mk = 1; mk < 16; mk <<= 1) rsum += __shfl_xor(rsum, mk);
            l_run[r] = l_run[r] * alpha + rsum;
            #pragma unroll
            for (int d16 = 0; d16 < 4; ++d16) o_acc[d16][r] *= alpha;
            #pragma unroll
            for (int f = 0; f < 4; ++f) pw[(4 * g + r) * PAD + f * 16 + c] = f2bf(sf[f][r]);
        }
        asm volatile("" ::: "memory");
        #pragma unroll
        for (int ch = 0; ch < 2; ++ch) {
            bf16x8 pf = *(const bf16x8*)&pw[c * PAD + ch * 32 + g * 8];
            #pragma unroll
            for (int d16 = 0; d16 < 4; ++d16) {
                bf16x8 vf = *(const bf16x8*)&vT_lds[(d16 * 16 + c) * PAD + ch * 32 + g * 8];
                o_acc[d16] = __builtin_amdgcn_mfma_f32_16x16x32_bf16(pf, vf, o_acc[d16], 0, 0, 0);
            }
        }
        __syncthreads();
    }
    #pragma unroll
    for (int r = 0; r < 4; ++r) {
        const float inv = 1.0f / l_run[r];
        float* orow = Op + base + (size_t)(q0 + 4 * g + r) * DH;
        #pragma unroll
        for (int d16 = 0; d16 < 4; ++d16) orow[d16 * 16 + c] = o_acc[d16][r] * inv;
    }
}

extern "C" void kernel_launch(void* const* d_in, const int* in_sizes, int n_in,
                              void* d_out, int out_size, void* d_ws, size_t ws_size,
                              hipStream_t stream) {
    const float* q = (const float*)d_in[0];
    const float* k = (const float*)d_in[1];
    const float* v = (const float*)d_in[2];
    float* out = (float*)d_out;
    const int bh = in_sizes[0] / (SEQ * DH);                // B*H = 64
    const size_t nelem = (size_t)bh * SEQ * DH;
    const size_t need  = nelem * 2 * 2;                     // Kb + VTb, bf16

    if (ws_size >= need) {
        short* Kb  = (short*)d_ws;
        short* VTb = Kb + nelem;
        int n8 = (int)(nelem / 8);
        prep_k_bf16   <<<(n8 + 255) / 256, 256, 0, stream>>>(k, Kb, n8);
        prep_v_transpose<<<bh * (SEQ / 64), 256, 0, stream>>>(v, VTb);
        attn_fwd_v4   <<<(SEQ / QB) * bh, 256, 0, stream>>>(q, Kb, VTb, out);
    } else {
        attn_fwd_v3   <<<(SEQ / QB) * bh, 256, 0, stream>>>(q, k, v, out);
    }
}

// Round 11
// 285.801 us; speedup vs baseline: 1.3606x; 1.0362x over previous
//
#include <hip/hip_runtime.h>
#include <hip/hip_bf16.h>
#include <stdint.h>

#define SEQ 2048
#define DH 64
#define QB 64           // q rows per block (16 per wave)
#define KB 64           // kv rows per tile
#define NT (SEQ / KB)
#define PAD 72          // (fallback kernel only)

typedef __attribute__((ext_vector_type(8))) short bf16x8;
typedef __attribute__((ext_vector_type(4))) short bf16x4;
typedef __attribute__((ext_vector_type(4))) float f32x4;

__device__ __forceinline__ short f2bf(float x) {
    union { __hip_bfloat16 h; short s; } u; u.h = __float2bfloat16(x); return u.s;
}
__device__ __forceinline__ int packbf(float lo, float hi) {
    return (int)((unsigned)(unsigned short)f2bf(lo) | ((unsigned)(unsigned short)f2bf(hi) << 16));
}

// ---- global_load_lds: 16B/lane, dest = wave-uniform LDS base + lane*16 ----
typedef __attribute__((address_space(3))) unsigned int       lds_u32;
typedef const __attribute__((address_space(1))) unsigned int g_u32;
__device__ __forceinline__ void gload16(const void* g, const void* lds_base) {
    __builtin_amdgcn_global_load_lds((g_u32*)(unsigned long long)g,
                                     (lds_u32*)(unsigned int)(unsigned long long)lds_base,
                                     16, 0, 0);
}

// ================= fused prep: K->bf16 convert + V->bf16 transpose =================
__global__ __launch_bounds__(256)
void prep_fused(const float* __restrict__ K, const float* __restrict__ V,
                short* __restrict__ Kb, short* __restrict__ VT,
                int nKblocks, int n8) {
    if ((int)blockIdx.x < nKblocks) {
        int i = blockIdx.x * 256 + threadIdx.x;
        if (i >= n8) return;
        float4 a = ((const float4*)K)[i * 2], b = ((const float4*)K)[i * 2 + 1];
        bf16x8 r;
        r[0]=f2bf(a.x); r[1]=f2bf(a.y); r[2]=f2bf(a.z); r[3]=f2bf(a.w);
        r[4]=f2bf(b.x); r[5]=f2bf(b.y); r[6]=f2bf(b.z); r[7]=f2bf(b.w);
        ((bf16x8*)Kb)[i] = r;
        return;
    }
    // ---- V transpose path ----
    __shared__ short tile[64][72];
    const int vb   = blockIdx.x - nKblocks;
    const int head = vb >> 5;
    const int s0   = (vb & 31) * 64;
    const int tid  = threadIdx.x;
    {
        const int r = tid >> 2, cb = (tid & 3) * 16;
        const float* src = V + ((size_t)head * SEQ + s0 + r) * DH + cb;
        float4 f0 = ((const float4*)src)[0], f1 = ((const float4*)src)[1];
        float4 f2 = ((const float4*)src)[2], f3 = ((const float4*)src)[3];
        bf16x8 lo, hi;
        lo[0]=f2bf(f0.x); lo[1]=f2bf(f0.y); lo[2]=f2bf(f0.z); lo[3]=f2bf(f0.w);
        lo[4]=f2bf(f1.x); lo[5]=f2bf(f1.y); lo[6]=f2bf(f1.z); lo[7]=f2bf(f1.w);
        hi[0]=f2bf(f2.x); hi[1]=f2bf(f2.y); hi[2]=f2bf(f2.z); hi[3]=f2bf(f2.w);
        hi[4]=f2bf(f3.x); hi[5]=f2bf(f3.y); hi[6]=f2bf(f3.z); hi[7]=f2bf(f3.w);
        *(bf16x8*)&tile[r][cb]     = lo;
        *(bf16x8*)&tile[r][cb + 8] = hi;
    }
    __syncthreads();
    {
        const int d = tid >> 2, sb = (tid & 3) * 16;
        bf16x8 lo, hi;
        #pragma unroll
        for (int j = 0; j < 8; ++j) lo[j] = tile[sb + j][d];
        #pragma unroll
        for (int j = 0; j < 8; ++j) hi[j] = tile[sb + 8 + j][d];
        short* dst = VT + ((size_t)head * DH + d) * SEQ + s0 + sb;
        *(bf16x8*)dst       = lo;
        *(bf16x8*)(dst + 8) = hi;
    }
}

// ================= main attention (v5) =================
__global__ __launch_bounds__(256)
void attn_fwd_v5(const float* __restrict__ Qp,
                 const short* __restrict__ Kb,
                 const short* __restrict__ VTb,
                 float* __restrict__ Op) {
    __shared__ __align__(16) short k_lds [2][KB * DH];   // [kv][d], swizzled content
    __shared__ __align__(16) short vt_lds[2][DH * KB];   // [d][kv], swizzled content

    const int tid  = threadIdx.x;
    const int wave = tid >> 6;
    const int lane = tid & 63;
    const int g    = lane >> 4;       // 0..3
    const int c    = lane & 15;       // 0..15

    // T1 chunked XCD swizzle (bijective: grid%8==0)
    const int chunk = gridDim.x >> 3;
    const int L     = (blockIdx.x & 7) * chunk + (blockIdx.x >> 3);
    const int head  = L >> 5;
    const int q0    = (L & 31) * QB + wave * 16;

    const size_t baseF  = (size_t)head * SEQ * DH;        // fp32 Q/O
    const short* Kh  = Kb  + baseF;                       // [s][d] bf16
    const short* VTh = VTb + (size_t)head * DH * SEQ;     // [d][s] bf16

    // Q fragments (B-operand: col=c=q, k=8g+j), scale = 1/8 * log2(e)
    const float qscale = 0.125f * 1.44269504088896f;
    bf16x8 qf[2];
    {
        const float* qrow = Qp + baseF + (size_t)(q0 + c) * DH;
        #pragma unroll
        for (int ch = 0; ch < 2; ++ch) {
            float4 a = *(const float4*)(qrow + ch * 32 + g * 8);
            float4 b = *(const float4*)(qrow + ch * 32 + g * 8 + 4);
            bf16x8 r;
            r[0]=f2bf(a.x*qscale); r[1]=f2bf(a.y*qscale); r[2]=f2bf(a.z*qscale); r[3]=f2bf(a.w*qscale);
            r[4]=f2bf(b.x*qscale); r[5]=f2bf(b.y*qscale); r[6]=f2bf(b.z*qscale); r[7]=f2bf(b.w*qscale);
            qf[ch] = r;
        }
    }

    f32x4 o_acc[4] = {};                 // C: row=4g+r=q-row, col=c=d-col
    float m_run = -1e30f, l_run = 0.f;   // lane's softmax row = q0 + c

    // loop-invariant LDS read offsets: row (16f|16d16)+c, swizzled 16B granule
    const int kbase0 = c * DH + (((0 + g) ^ (c & 7)) << 3);   // ch=0
    const int kbase1 = c * DH + (((4 + g) ^ (c & 7)) << 3);   // ch=1

    // P redistribute constants
    const int srcb = c + ((g & 1) << 5);
    const bool hi2 = (g >> 1) != 0;

    // staging geometry (pre-swizzled global source, linear LDS dest)
    const int r8   = lane >> 3, c8 = lane & 7;
    const int csw8 = ((c8 ^ r8) << 3);
    const int rowb = 16 * wave;

    #define STAGE(T, BUF) do {                                                        \
        _Pragma("unroll")                                                             \
        for (int i = 0; i < 2; ++i) {                                                 \
            gload16(Kh  + ((size_t)((T) * KB + rowb + 8 * i + r8) * DH + csw8),       \
                    &k_lds[BUF][(rowb + 8 * i) * DH]);                                \
            gload16(VTh + ((size_t)(rowb + 8 * i + r8) * SEQ + (T) * KB + csw8),      \
                    &vt_lds[BUF][(rowb + 8 * i) * DH]);                               \
        } } while (0)

    #define TILE_BODY(T, BUF) do {                                                   \
        if ((T) + 1 < NT) STAGE((T) + 1, (BUF) ^ 1);                                  \
        f32x4 sf[4];                                                                  \
        __builtin_amdgcn_s_setprio(1);                                                \
        _Pragma("unroll")                                                             \
        for (int f = 0; f < 4; ++f) {                                                 \
            f32x4 acc = {0.f, 0.f, 0.f, 0.f};                                         \
            {   bf16x8 kf = *(const bf16x8*)&k_lds[BUF][f * 1024 + kbase0];           \
                acc = __builtin_amdgcn_mfma_f32_16x16x32_bf16(kf, qf[0], acc, 0,0,0); \
                kf = *(const bf16x8*)&k_lds[BUF][f * 1024 + kbase1];                  \
                acc = __builtin_amdgcn_mfma_f32_16x16x32_bf16(kf, qf[1], acc, 0,0,0); \
            }                                                                         \
            sf[f] = acc;                                                              \
        }                                                                             \
        __builtin_amdgcn_s_setprio(0);                                                \
        float mx = sf[0][0];                                                          \
        _Pragma("unroll")                                                             \
        for (int f = 0; f < 4; ++f)                                                   \
            _Pragma("unroll")                                                         \
            for (int r = 0; r < 4; ++r) mx = fmaxf(mx, sf[f][r]);                     \
        mx = fmaxf(mx, __shfl_xor(mx, 16));                                           \
        mx = fmaxf(mx, __shfl_xor(mx, 32));                                           \
        if (!__all(mx - m_run <= 8.0f)) {            /* T13 defer-max */              \
            const float mnew  = fmaxf(m_run, mx);                                     \
            const float alpha = exp2f(m_run - mnew);                                  \
            float al[4];                                                              \
            _Pragma("unroll")                                                         \
            for (int r = 0; r < 4; ++r) al[r] = __shfl(alpha, 4 * g + r);             \
            _Pragma("unroll")                                                         \
            for (int d16 = 0; d16 < 4; ++d16)                                         \
                _Pragma("unroll")                                                     \
                for (int r = 0; r < 4; ++r) o_acc[d16][r] *= al[r];                   \
            l_run *= alpha;                                                           \
            m_run = mnew;                                                             \
        }                                                                             \
        float rsum = 0.f;                                                             \
        _Pragma("unroll")                                                             \
        for (int f = 0; f < 4; ++f)                                                   \
            _Pragma("unroll")                                                         \
            for (int r = 0; r < 4; ++r) {                                             \
                float p = exp2f(sf[f][r] - m_run);                                    \
                sf[f][r] = p; rsum += p;                                              \
            }                                                                         \
        rsum += __shfl_xor(rsum, 16);                                                 \
        rsum += __shfl_xor(rsum, 32);                                                 \
        l_run += rsum;                                                                \
        int pd[4][2];                                                                 \
        _Pragma("unroll")                                                             \
        for (int f = 0; f < 4; ++f) {                                                 \
            pd[f][0] = packbf(sf[f][0], sf[f][1]);                                    \
            pd[f][1] = packbf(sf[f][2], sf[f][3]);                                    \
        }                                                                             \
        int a_dw[2][4];                                                               \
        _Pragma("unroll")                                                             \
        for (int ch = 0; ch < 2; ++ch)                                                \
            _Pragma("unroll")                                                         \
            for (int jt = 0; jt < 4; ++jt) {                                          \
                int src = srcb + ((jt >> 1) << 4);                                    \
                int tA = __shfl(pd[2 * ch][jt & 1], src);                             \
                int tB = __shfl(pd[2 * ch + 1][jt & 1], src);                         \
                a_dw[ch][jt] = hi2 ? tB : tA;                                         \
            }                                                                         \
        __builtin_amdgcn_s_setprio(1);                                                \
        _Pragma("unroll")                                                             \
        for (int ch = 0; ch < 2; ++ch) {                                              \
            union { int d[4]; bf16x8 v; } au;                                         \
            _Pragma("unroll")                                                         \
            for (int jt = 0; jt < 4; ++jt) au.d[jt] = a_dw[ch][jt];                   \
            _Pragma("unroll")                                                         \
            for (int d16 = 0; d16 < 4; ++d16) {                                       \
                bf16x8 vf = *(const bf16x8*)&vt_lds[BUF][d16 * 1024 +                 \
                                                         (ch ? kbase1 : kbase0)];     \
                o_acc[d16] = __builtin_amdgcn_mfma_f32_16x16x32_bf16(au.v, vf,        \
                                                                o_acc[d16], 0,0,0);   \
            }                                                                         \
        }                                                                             \
        __builtin_amdgcn_s_setprio(0);                                                \
        __syncthreads();                                                              \
    } while (0)

    STAGE(0, 0);
    __syncthreads();

    for (int t = 0; t < NT; t += 2) {      // unroll-2: BUF literal -> static LDS addrs
        TILE_BODY(t, 0);
        TILE_BODY(t + 1, 1);
    }
    #undef TILE_BODY
    #undef STAGE

    // ---- epilogue ----
    #pragma unroll
    for (int r = 0; r < 4; ++r) {
        float li  = __shfl(l_run, 4 * g + r);
        float inv = 1.0f / li;
        float* orow = Op + baseF + (size_t)(q0 + 4 * g + r) * DH;
        #pragma unroll
        for (int d16 = 0; d16 < 4; ++d16)
            orow[d16 * 16 + c] = o_acc[d16][r] * inv;
    }
}

// ================= fallback (v3, known-pass) — only if ws too small =================
__global__ __launch_bounds__(256)
void attn_fwd_v3(const float* __restrict__ Qp, const float* __restrict__ Kp,
                 const float* __restrict__ Vp, float* __restrict__ Op) {
    __shared__ __align__(16) short k_lds[KB * PAD];
    __shared__ __align__(16) short vT_lds[DH * PAD];
    __shared__ __align__(16) short p_lds[4 * 16 * PAD];
    const int tid = threadIdx.x, wave = tid >> 6, lane = tid & 63;
    const int g = lane >> 4, c = lane & 15;
    const int chunk = gridDim.x >> 3;
    const int L = (blockIdx.x & 7) * chunk + (blockIdx.x >> 3);
    const int head = L >> 5;
    const int q0 = (L & 31) * QB + wave * 16;
    const size_t base = (size_t)head * SEQ * DH;
    const float qscale = 0.125f * 1.44269504088896f;
    bf16x8 qf[2];
    {
        const float* qrow = Qp + base + (size_t)(q0 + c) * DH;
        #pragma unroll
        for (int ch = 0; ch < 2; ++ch) {
            float4 a = *(const float4*)(qrow + ch * 32 + g * 8);
            float4 b = *(const float4*)(qrow + ch * 32 + g * 8 + 4);
            bf16x8 r;
            r[0]=f2bf(a.x*qscale); r[1]=f2bf(a.y*qscale); r[2]=f2bf(a.z*qscale); r[3]=f2bf(a.w*qscale);
            r[4]=f2bf(b.x*qscale); r[5]=f2bf(b.y*qscale); r[6]=f2bf(b.z*qscale); r[7]=f2bf(b.w*qscale);
            qf[ch] = r;
        }
    }
    f32x4 o_acc[4] = {};
    float m_run[4], l_run[4];
    #pragma unroll
    for (int r = 0; r < 4; ++r) { m_run[r] = -1e30f; l_run[r] = 0.f; }
    const int krow = tid >> 2, kcol = (tid & 3) << 4;
    const int vrow = (tid >> 4) << 2, vcol = (tid & 15) << 2;
    const float* kptr = Kp + base + (size_t)krow * DH + kcol;
    const float* vptr = Vp + base + (size_t)vrow * DH + vcol;
    float4 kr[4], vr[4];
    #pragma unroll
    for (int i = 0; i < 4; ++i) { kr[i] = ((const float4*)kptr)[i]; vr[i] = *(const float4*)(vptr + i * DH); }
    for (int t = 0; t < NT; ++t) {
        {
            bf16x8 lo, hi;
            lo[0]=f2bf(kr[0].x); lo[1]=f2bf(kr[0].y); lo[2]=f2bf(kr[0].z); lo[3]=f2bf(kr[0].w);
            lo[4]=f2bf(kr[1].x); lo[5]=f2bf(kr[1].y); lo[6]=f2bf(kr[1].z); lo[7]=f2bf(kr[1].w);
            hi[0]=f2bf(kr[2].x); hi[1]=f2bf(kr[2].y); hi[2]=f2bf(kr[2].z); hi[3]=f2bf(kr[2].w);
            hi[4]=f2bf(kr[3].x); hi[5]=f2bf(kr[3].y); hi[6]=f2bf(kr[3].z); hi[7]=f2bf(kr[3].w);
            *(bf16x8*)&k_lds[krow * PAD + kcol] = lo;
            *(bf16x8*)&k_lds[krow * PAD + kcol + 8] = hi;
            #pragma unroll
            for (int j = 0; j < 4; ++j) {
                bf16x4 w;
                w[0]=f2bf(((const float*)&vr[0])[j]); w[1]=f2bf(((const float*)&vr[1])[j]);
                w[2]=f2bf(((const float*)&vr[2])[j]); w[3]=f2bf(((const float*)&vr[3])[j]);
                *(bf16x4*)&vT_lds[(vcol + j) * PAD + vrow] = w;
            }
        }
        __syncthreads();
        if (t + 1 < NT) {
            const float* kn = kptr + (size_t)(t + 1) * KB * DH;
            const float* vn = vptr + (size_t)(t + 1) * KB * DH;
            #pragma unroll
            for (int i = 0; i < 4; ++i) { kr[i] = ((const float4*)kn)[i]; vr[i] = *(const float4*)(vn + i * DH); }
        }
        f32x4 sf[4];
        #pragma unroll
        for (int f = 0; f < 4; ++f) {
            f32x4 acc = {0.f, 0.f, 0.f, 0.f};
            #pragma unroll
            for (int ch = 0; ch < 2; ++ch) {
                bf16x8 kf = *(const bf16x8*)&k_lds[(f * 16 + c) * PAD + ch * 32 + g * 8];
                acc = __builtin_amdgcn_mfma_f32_16x16x32_bf16(qf[ch], kf, acc, 0, 0, 0);
            }
            sf[f] = acc;
        }
        short* pw = &p_lds[wave * 16 * PAD];
        #pragma unroll
        for (int r = 0; r < 4; ++r) {
            float mx = fmaxf(fmaxf(sf[0][r], sf[1][r]), fmaxf(sf[2][r], sf[3][r]));
            #pragma unroll
            for (int mk = 1; mk < 16; mk <<= 1) mx = fmaxf(mx, __shfl_xor(mx, mk));
            const float mnew = fmaxf(m_run[r], mx);
            const float alpha = exp2f(m_run[r] - mnew);
            m_run[r] = mnew;
            float rsum = 0.f;
            #pragma unroll
            for (int f = 0; f < 4; ++f) { float p = exp2f(sf[f][r] - mnew); sf[f][r] = p; rsum += p; }
            #pragma unroll
            for (int mk = 1; mk < 16; mk <<= 1) rsum += __shfl_xor(rsum, mk);
            l_run[r] = l_run[r] * alpha + rsum;
            #pragma unroll
            for (int d16 = 0; d16 < 4; ++d16) o_acc[d16][r] *= alpha;
            #pragma unroll
            for (int f = 0; f < 4; ++f) pw[(4 * g + r) * PAD + f * 16 + c] = f2bf(sf[f][r]);
        }
        asm volatile("" ::: "memory");
        #pragma unroll
        for (int ch = 0; ch < 2; ++ch) {
            bf16x8 pf = *(const bf16x8*)&pw[c * PAD + ch * 32 + g * 8];
            #pragma unroll
            for (int d16 = 0; d16 < 4; ++d16) {
                bf16x8 vf = *(const bf16x8*)&vT_lds[(d16 * 16 + c) * PAD + ch * 32 + g * 8];
                o_acc[d16] = __builtin_amdgcn_mfma_f32_16x16x32_bf16(pf, vf, o_acc[d16], 0, 0, 0);
            }
        }
        __syncthreads();
    }
    #pragma unroll
    for (int r = 0; r < 4; ++r) {
        const float inv = 1.0f / l_run[r];
        float* orow = Op + base + (size_t)(q0 + 4 * g + r) * DH;
        #pragma unroll
        for (int d16 = 0; d16 < 4; ++d16) orow[d16 * 16 + c] = o_acc[d16][r] * inv;
    }
}

extern "C" void kernel_launch(void* const* d_in, const int* in_sizes, int n_in,
                              void* d_out, int out_size, void* d_ws, size_t ws_size,
                              hipStream_t stream) {
    const float* q = (const float*)d_in[0];
    const float* k = (const float*)d_in[1];
    const float* v = (const float*)d_in[2];
    float* out = (float*)d_out;
    const int bh = in_sizes[0] / (SEQ * DH);                // B*H = 64
    const size_t nelem = (size_t)bh * SEQ * DH;
    const size_t need  = nelem * 2 * 2;                     // Kb + VTb, bf16

    if (ws_size >= need) {
        short* Kb  = (short*)d_ws;
        short* VTb = Kb + nelem;
        const int n8       = (int)(nelem / 8);
        const int nKblocks = (n8 + 255) / 256;              // 8192
        const int nVblocks = bh * (SEQ / 64);               // 2048
        prep_fused <<<nKblocks + nVblocks, 256, 0, stream>>>(k, v, Kb, VTb, nKblocks, n8);
        attn_fwd_v5<<<(SEQ / QB) * bh, 256, 0, stream>>>(q, Kb, VTb, out);
    } else {
        attn_fwd_v3<<<(SEQ / QB) * bh, 256, 0, stream>>>(q, k, v, out);
    }
}

// Round 12
// 279.636 us; speedup vs baseline: 1.3906x; 1.0220x over previous
//
#include <hip/hip_runtime.h>
#include <hip/hip_bf16.h>
#include <stdint.h>

#define SEQ 2048
#define DH 64
#define QB 64           // q rows per block (16 per wave)
#define KB 64           // kv rows per tile
#define NT (SEQ / KB)
#define PAD 72          // (fallback kernel only)

typedef __attribute__((ext_vector_type(8))) short bf16x8;
typedef __attribute__((ext_vector_type(4))) short bf16x4;
typedef __attribute__((ext_vector_type(4))) float f32x4;

__device__ __forceinline__ short f2bf(float x) {
    union { __hip_bfloat16 h; short s; } u; u.h = __float2bfloat16(x); return u.s;
}
__device__ __forceinline__ int packbf(float lo, float hi) {
    return (int)((unsigned)(unsigned short)f2bf(lo) | ((unsigned)(unsigned short)f2bf(hi) << 16));
}

// ---- global_load_lds: 16B/lane, dest = wave-uniform LDS base + lane*16 ----
typedef __attribute__((address_space(3))) unsigned int       lds_u32;
typedef const __attribute__((address_space(1))) unsigned int g_u32;
__device__ __forceinline__ void gload16(const void* g, const void* lds_base) {
    __builtin_amdgcn_global_load_lds((g_u32*)(unsigned long long)g,
                                     (lds_u32*)(unsigned int)(unsigned long long)lds_base,
                                     16, 0, 0);
}

// ================= fused prep: K->bf16 convert + V->bf16 transpose =================
__global__ __launch_bounds__(256)
void prep_fused(const float* __restrict__ K, const float* __restrict__ V,
                short* __restrict__ Kb, short* __restrict__ VT,
                int nKblocks, int n8) {
    if ((int)blockIdx.x < nKblocks) {
        int i = blockIdx.x * 256 + threadIdx.x;
        if (i >= n8) return;
        float4 a = ((const float4*)K)[i * 2], b = ((const float4*)K)[i * 2 + 1];
        bf16x8 r;
        r[0]=f2bf(a.x); r[1]=f2bf(a.y); r[2]=f2bf(a.z); r[3]=f2bf(a.w);
        r[4]=f2bf(b.x); r[5]=f2bf(b.y); r[6]=f2bf(b.z); r[7]=f2bf(b.w);
        ((bf16x8*)Kb)[i] = r;
        return;
    }
    // ---- V transpose path ----
    __shared__ short tile[64][72];
    const int vb   = blockIdx.x - nKblocks;
    const int head = vb >> 5;
    const int s0   = (vb & 31) * 64;
    const int tid  = threadIdx.x;
    {
        const int r = tid >> 2, cb = (tid & 3) * 16;
        const float* src = V + ((size_t)head * SEQ + s0 + r) * DH + cb;
        float4 f0 = ((const float4*)src)[0], f1 = ((const float4*)src)[1];
        float4 f2 = ((const float4*)src)[2], f3 = ((const float4*)src)[3];
        bf16x8 lo, hi;
        lo[0]=f2bf(f0.x); lo[1]=f2bf(f0.y); lo[2]=f2bf(f0.z); lo[3]=f2bf(f0.w);
        lo[4]=f2bf(f1.x); lo[5]=f2bf(f1.y); lo[6]=f2bf(f1.z); lo[7]=f2bf(f1.w);
        hi[0]=f2bf(f2.x); hi[1]=f2bf(f2.y); hi[2]=f2bf(f2.z); hi[3]=f2bf(f2.w);
        hi[4]=f2bf(f3.x); hi[5]=f2bf(f3.y); hi[6]=f2bf(f3.z); hi[7]=f2bf(f3.w);
        *(bf16x8*)&tile[r][cb]     = lo;
        *(bf16x8*)&tile[r][cb + 8] = hi;
    }
    __syncthreads();
    {
        const int d = tid >> 2, sb = (tid & 3) * 16;
        bf16x8 lo, hi;
        #pragma unroll
        for (int j = 0; j < 8; ++j) lo[j] = tile[sb + j][d];
        #pragma unroll
        for (int j = 0; j < 8; ++j) hi[j] = tile[sb + 8 + j][d];
        short* dst = VT + ((size_t)head * DH + d) * SEQ + s0 + sb;
        *(bf16x8*)dst       = lo;
        *(bf16x8*)(dst + 8) = hi;
    }
}

// ================= main attention (v6 = v5 + launch_bounds(256,4)) =================
// R11 evidence: VGPR_Count=60 (8-wave register target) while LDS caps occupancy
// at 5 blocks/CU anyway -> allocator starves the unroll-2 body and rematerializes
// (~280K unexplained VALU cycles/SIMD). Give it a 128-VGPR budget @ 4 blocks/CU.
__global__ __launch_bounds__(256, 4)
void attn_fwd_v6(const float* __restrict__ Qp,
                 const short* __restrict__ Kb,
                 const short* __restrict__ VTb,
                 float* __restrict__ Op) {
    __shared__ __align__(16) short k_lds [2][KB * DH];   // [kv][d], swizzled content
    __shared__ __align__(16) short vt_lds[2][DH * KB];   // [d][kv], swizzled content

    const int tid  = threadIdx.x;
    const int wave = tid >> 6;
    const int lane = tid & 63;
    const int g    = lane >> 4;       // 0..3
    const int c    = lane & 15;       // 0..15

    // T1 chunked XCD swizzle (bijective: grid%8==0)
    const int chunk = gridDim.x >> 3;
    const int L     = (blockIdx.x & 7) * chunk + (blockIdx.x >> 3);
    const int head  = L >> 5;
    const int q0    = (L & 31) * QB + wave * 16;

    const size_t baseF  = (size_t)head * SEQ * DH;        // fp32 Q/O
    const short* Kh  = Kb  + baseF;                       // [s][d] bf16
    const short* VTh = VTb + (size_t)head * DH * SEQ;     // [d][s] bf16

    // Q fragments (B-operand: col=c=q, k=8g+j), scale = 1/8 * log2(e)
    const float qscale = 0.125f * 1.44269504088896f;
    bf16x8 qf[2];
    {
        const float* qrow = Qp + baseF + (size_t)(q0 + c) * DH;
        #pragma unroll
        for (int ch = 0; ch < 2; ++ch) {
            float4 a = *(const float4*)(qrow + ch * 32 + g * 8);
            float4 b = *(const float4*)(qrow + ch * 32 + g * 8 + 4);
            bf16x8 r;
            r[0]=f2bf(a.x*qscale); r[1]=f2bf(a.y*qscale); r[2]=f2bf(a.z*qscale); r[3]=f2bf(a.w*qscale);
            r[4]=f2bf(b.x*qscale); r[5]=f2bf(b.y*qscale); r[6]=f2bf(b.z*qscale); r[7]=f2bf(b.w*qscale);
            qf[ch] = r;
        }
    }

    f32x4 o_acc[4] = {};                 // C: row=4g+r=q-row, col=c=d-col
    float m_run = -1e30f, l_run = 0.f;   // lane's softmax row = q0 + c

    // loop-invariant LDS read offsets: row (16f|16d16)+c, swizzled 16B granule
    const int kbase0 = c * DH + (((0 + g) ^ (c & 7)) << 3);   // ch=0
    const int kbase1 = c * DH + (((4 + g) ^ (c & 7)) << 3);   // ch=1

    // P redistribute constants
    const int srcb = c + ((g & 1) << 5);
    const bool hi2 = (g >> 1) != 0;

    // staging geometry (pre-swizzled global source, linear LDS dest)
    const int r8   = lane >> 3, c8 = lane & 7;
    const int csw8 = ((c8 ^ r8) << 3);
    const int rowb = 16 * wave;

    #define STAGE(T, BUF) do {                                                        \
        _Pragma("unroll")                                                             \
        for (int i = 0; i < 2; ++i) {                                                 \
            gload16(Kh  + ((size_t)((T) * KB + rowb + 8 * i + r8) * DH + csw8),       \
                    &k_lds[BUF][(rowb + 8 * i) * DH]);                                \
            gload16(VTh + ((size_t)(rowb + 8 * i + r8) * SEQ + (T) * KB + csw8),      \
                    &vt_lds[BUF][(rowb + 8 * i) * DH]);                               \
        } } while (0)

    #define TILE_BODY(T, BUF) do {                                                   \
        if ((T) + 1 < NT) STAGE((T) + 1, (BUF) ^ 1);                                  \
        f32x4 sf[4];                                                                  \
        __builtin_amdgcn_s_setprio(1);                                                \
        _Pragma("unroll")                                                             \
        for (int f = 0; f < 4; ++f) {                                                 \
            f32x4 acc = {0.f, 0.f, 0.f, 0.f};                                         \
            {   bf16x8 kf = *(const bf16x8*)&k_lds[BUF][f * 1024 + kbase0];           \
                acc = __builtin_amdgcn_mfma_f32_16x16x32_bf16(kf, qf[0], acc, 0,0,0); \
                kf = *(const bf16x8*)&k_lds[BUF][f * 1024 + kbase1];                  \
                acc = __builtin_amdgcn_mfma_f32_16x16x32_bf16(kf, qf[1], acc, 0,0,0); \
            }                                                                         \
            sf[f] = acc;                                                              \
        }                                                                             \
        __builtin_amdgcn_s_setprio(0);                                                \
        float mx = sf[0][0];                                                          \
        _Pragma("unroll")                                                             \
        for (int f = 0; f < 4; ++f)                                                   \
            _Pragma("unroll")                                                         \
            for (int r = 0; r < 4; ++r) mx = fmaxf(mx, sf[f][r]);                     \
        mx = fmaxf(mx, __shfl_xor(mx, 16));                                           \
        mx = fmaxf(mx, __shfl_xor(mx, 32));                                           \
        if (!__all(mx - m_run <= 8.0f)) {            /* T13 defer-max */              \
            const float mnew  = fmaxf(m_run, mx);                                     \
            const float alpha = exp2f(m_run - mnew);                                  \
            float al[4];                                                              \
            _Pragma("unroll")                                                         \
            for (int r = 0; r < 4; ++r) al[r] = __shfl(alpha, 4 * g + r);             \
            _Pragma("unroll")                                                         \
            for (int d16 = 0; d16 < 4; ++d16)                                         \
                _Pragma("unroll")                                                     \
                for (int r = 0; r < 4; ++r) o_acc[d16][r] *= al[r];                   \
            l_run *= alpha;                                                           \
            m_run = mnew;                                                             \
        }                                                                             \
        float rsum = 0.f;                                                             \
        _Pragma("unroll")                                                             \
        for (int f = 0; f < 4; ++f)                                                   \
            _Pragma("unroll")                                                         \
            for (int r = 0; r < 4; ++r) {                                             \
                float p = exp2f(sf[f][r] - m_run);                                    \
                sf[f][r] = p; rsum += p;                                              \
            }                                                                         \
        rsum += __shfl_xor(rsum, 16);                                                 \
        rsum += __shfl_xor(rsum, 32);                                                 \
        l_run += rsum;                                                                \
        int pd[4][2];                                                                 \
        _Pragma("unroll")                                                             \
        for (int f = 0; f < 4; ++f) {                                                 \
            pd[f][0] = packbf(sf[f][0], sf[f][1]);                                    \
            pd[f][1] = packbf(sf[f][2], sf[f][3]);                                    \
        }                                                                             \
        int a_dw[2][4];                                                               \
        _Pragma("unroll")                                                             \
        for (int ch = 0; ch < 2; ++ch)                                                \
            _Pragma("unroll")                                                         \
            for (int jt = 0; jt < 4; ++jt) {                                          \
                int src = srcb + ((jt >> 1) << 4);                                    \
                int tA = __shfl(pd[2 * ch][jt & 1], src);                             \
                int tB = __shfl(pd[2 * ch + 1][jt & 1], src);                         \
                a_dw[ch][jt] = hi2 ? tB : tA;                                         \
            }                                                                         \
        __builtin_amdgcn_s_setprio(1);                                                \
        _Pragma("unroll")                                                             \
        for (int ch = 0; ch < 2; ++ch) {                                              \
            union { int d[4]; bf16x8 v; } au;                                         \
            _Pragma("unroll")                                                         \
            for (int jt = 0; jt < 4; ++jt) au.d[jt] = a_dw[ch][jt];                   \
            _Pragma("unroll")                                                         \
            for (int d16 = 0; d16 < 4; ++d16) {                                       \
                bf16x8 vf = *(const bf16x8*)&vt_lds[BUF][d16 * 1024 +                 \
                                                         (ch ? kbase1 : kbase0)];     \
                o_acc[d16] = __builtin_amdgcn_mfma_f32_16x16x32_bf16(au.v, vf,        \
                                                                o_acc[d16], 0,0,0);   \
            }                                                                         \
        }                                                                             \
        __builtin_amdgcn_s_setprio(0);                                                \
        __syncthreads();                                                              \
    } while (0)

    STAGE(0, 0);
    __syncthreads();

    for (int t = 0; t < NT; t += 2) {      // unroll-2: BUF literal -> static LDS addrs
        TILE_BODY(t, 0);
        TILE_BODY(t + 1, 1);
    }
    #undef TILE_BODY
    #undef STAGE

    // ---- epilogue ----
    #pragma unroll
    for (int r = 0; r < 4; ++r) {
        float li  = __shfl(l_run, 4 * g + r);
        float inv = 1.0f / li;
        float* orow = Op + baseF + (size_t)(q0 + 4 * g + r) * DH;
        #pragma unroll
        for (int d16 = 0; d16 < 4; ++d16)
            orow[d16 * 16 + c] = o_acc[d16][r] * inv;
    }
}

// ================= fallback (v3, known-pass) — only if ws too small =================
__global__ __launch_bounds__(256)
void attn_fwd_v3(const float* __restrict__ Qp, const float* __restrict__ Kp,
                 const float* __restrict__ Vp, float* __restrict__ Op) {
    __shared__ __align__(16) short k_lds[KB * PAD];
    __shared__ __align__(16) short vT_lds[DH * PAD];
    __shared__ __align__(16) short p_lds[4 * 16 * PAD];
    const int tid = threadIdx.x, wave = tid >> 6, lane = tid & 63;
    const int g = lane >> 4, c = lane & 15;
    const int chunk = gridDim.x >> 3;
    const int L = (blockIdx.x & 7) * chunk + (blockIdx.x >> 3);
    const int head = L >> 5;
    const int q0 = (L & 31) * QB + wave * 16;
    const size_t base = (size_t)head * SEQ * DH;
    const float qscale = 0.125f * 1.44269504088896f;
    bf16x8 qf[2];
    {
        const float* qrow = Qp + base + (size_t)(q0 + c) * DH;
        #pragma unroll
        for (int ch = 0; ch < 2; ++ch) {
            float4 a = *(const float4*)(qrow + ch * 32 + g * 8);
            float4 b = *(const float4*)(qrow + ch * 32 + g * 8 + 4);
            bf16x8 r;
            r[0]=f2bf(a.x*qscale); r[1]=f2bf(a.y*qscale); r[2]=f2bf(a.z*qscale); r[3]=f2bf(a.w*qscale);
            r[4]=f2bf(b.x*qscale); r[5]=f2bf(b.y*qscale); r[6]=f2bf(b.z*qscale); r[7]=f2bf(b.w*qscale);
            qf[ch] = r;
        }
    }
    f32x4 o_acc[4] = {};
    float m_run[4], l_run[4];
    #pragma unroll
    for (int r = 0; r < 4; ++r) { m_run[r] = -1e30f; l_run[r] = 0.f; }
    const int krow = tid >> 2, kcol = (tid & 3) << 4;
    const int vrow = (tid >> 4) << 2, vcol = (tid & 15) << 2;
    const float* kptr = Kp + base + (size_t)krow * DH + kcol;
    const float* vptr = Vp + base + (size_t)vrow * DH + vcol;
    float4 kr[4], vr[4];
    #pragma unroll
    for (int i = 0; i < 4; ++i) { kr[i] = ((const float4*)kptr)[i]; vr[i] = *(const float4*)(vptr + i * DH); }
    for (int t = 0; t < NT; ++t) {
        {
            bf16x8 lo, hi;
            lo[0]=f2bf(kr[0].x); lo[1]=f2bf(kr[0].y); lo[2]=f2bf(kr[0].z); lo[3]=f2bf(kr[0].w);
            lo[4]=f2bf(kr[1].x); lo[5]=f2bf(kr[1].y); lo[6]=f2bf(kr[1].z); lo[7]=f2bf(kr[1].w);
            hi[0]=f2bf(kr[2].x); hi[1]=f2bf(kr[2].y); hi[2]=f2bf(kr[2].z); hi[3]=f2bf(kr[2].w);
            hi[4]=f2bf(kr[3].x); hi[5]=f2bf(kr[3].y); hi[6]=f2bf(kr[3].z); hi[7]=f2bf(kr[3].w);
            *(bf16x8*)&k_lds[krow * PAD + kcol] = lo;
            *(bf16x8*)&k_lds[krow * PAD + kcol + 8] = hi;
            #pragma unroll
            for (int j = 0; j < 4; ++j) {
                bf16x4 w;
                w[0]=f2bf(((const float*)&vr[0])[j]); w[1]=f2bf(((const float*)&vr[1])[j]);
                w[2]=f2bf(((const float*)&vr[2])[j]); w[3]=f2bf(((const float*)&vr[3])[j]);
                *(bf16x4*)&vT_lds[(vcol + j) * PAD + vrow] = w;
            }
        }
        __syncthreads();
        if (t + 1 < NT) {
            const float* kn = kptr + (size_t)(t + 1) * KB * DH;
            const float* vn = vptr + (size_t)(t + 1) * KB * DH;
            #pragma unroll
            for (int i = 0; i < 4; ++i) { kr[i] = ((const float4*)kn)[i]; vr[i] = *(const float4*)(vn + i * DH); }
        }
        f32x4 sf[4];
        #pragma unroll
        for (int f = 0; f < 4; ++f) {
            f32x4 acc = {0.f, 0.f, 0.f, 0.f};
            #pragma unroll
            for (int ch = 0; ch < 2; ++ch) {
                bf16x8 kf = *(const bf16x8*)&k_lds[(f * 16 + c) * PAD + ch * 32 + g * 8];
                acc = __builtin_amdgcn_mfma_f32_16x16x32_bf16(qf[ch], kf, acc, 0, 0, 0);
            }
            sf[f] = acc;
        }
        short* pw = &p_lds[wave * 16 * PAD];
        #pragma unroll
        for (int r = 0; r < 4; ++r) {
            float mx = fmaxf(fmaxf(sf[0][r], sf[1][r]), fmaxf(sf[2][r], sf[3][r]));
            #pragma unroll
            for (int mk = 1; mk < 16; mk <<= 1) mx = fmaxf(mx, __shfl_xor(mx, mk));
            const float mnew = fmaxf(m_run[r], mx);
            const float alpha = exp2f(m_run[r] - mnew);
            m_run[r] = mnew;
            float rsum = 0.f;
            #pragma unroll
            for (int f = 0; f < 4; ++f) { float p = exp2f(sf[f][r] - mnew); sf[f][r] = p; rsum += p; }
            #pragma unroll
            for (int mk = 1; mk < 16; mk <<= 1) rsum += __shfl_xor(rsum, mk);
            l_run[r] = l_run[r] * alpha + rsum;
            #pragma unroll
            for (int d16 = 0; d16 < 4; ++d16) o_acc[d16][r] *= alpha;
            #pragma unroll
            for (int f = 0; f < 4; ++f) pw[(4 * g + r) * PAD + f * 16 + c] = f2bf(sf[f][r]);
        }
        asm volatile("" ::: "memory");
        #pragma unroll
        for (int ch = 0; ch < 2; ++ch) {
            bf16x8 pf = *(const bf16x8*)&pw[c * PAD + ch * 32 + g * 8];
            #pragma unroll
            for (int d16 = 0; d16 < 4; ++d16) {
                bf16x8 vf = *(const bf16x8*)&vT_lds[(d16 * 16 + c) * PAD + ch * 32 + g * 8];
                o_acc[d16] = __builtin_amdgcn_mfma_f32_16x16x32_bf16(pf, vf, o_acc[d16], 0, 0, 0);
            }
        }
        __syncthreads();
    }
    #pragma unroll
    for (int r = 0; r < 4; ++r) {
        const float inv = 1.0f / l_run[r];
        float* orow = Op + base + (size_t)(q0 + 4 * g + r) * DH;
        #pragma unroll
        for (int d16 = 0; d16 < 4; ++d16) orow[d16 * 16 + c] = o_acc[d16][r] * inv;
    }
}

extern "C" void kernel_launch(void* const* d_in, const int* in_sizes, int n_in,
                              void* d_out, int out_size, void* d_ws, size_t ws_size,
                              hipStream_t stream) {
    const float* q = (const float*)d_in[0];
    const float* k = (const float*)d_in[1];
    const float* v = (const float*)d_in[2];
    float* out = (float*)d_out;
    const int bh = in_sizes[0] / (SEQ * DH);                // B*H = 64
    const size_t nelem = (size_t)bh * SEQ * DH;
    const size_t need  = nelem * 2 * 2;                     // Kb + VTb, bf16

    if (ws_size >= need) {
        short* Kb  = (short*)d_ws;
        short* VTb = Kb + nelem;
        const int n8       = (int)(nelem / 8);
        const int nKblocks = (n8 + 255) / 256;              // 8192
        const int nVblocks = bh * (SEQ / 64);               // 2048
        prep_fused <<<nKblocks + nVblocks, 256, 0, stream>>>(k, v, Kb, VTb, nKblocks, n8);
        attn_fwd_v6<<<(SEQ / QB) * bh, 256, 0, stream>>>(q, Kb, VTb, out);
    } else {
        attn_fwd_v3<<<(SEQ / QB) * bh, 256, 0, stream>>>(q, k, v, out);
    }
}